// Round 1
// baseline (944.023 us; speedup 1.0000x reference)
//
#include <hip/hip_runtime.h>
#include <hip/hip_bf16.h>
#include <stdint.h>

// Problem constants
#define T_TOK 8192
#define DIM   1024
#define IDIM  2048
#define NEXP  8

typedef __bf16 bf16x8 __attribute__((ext_vector_type(8)));
typedef __bf16 bf16x4 __attribute__((ext_vector_type(4)));
typedef float  f32x4  __attribute__((ext_vector_type(4)));

// ---------------- workspace layout (bytes) ----------------
#define OFF_CNT    0          // int[8]   tokens per expert
#define OFF_PSUM   64         // float[8] softmax prob sums
#define OFF_CUR    128        // int[8]   assign cursors
#define OFF_SEGH   192        // int[16]  h-row start per segment (seg0=shared)
#define OFF_SEGC   256        // int[16]  row count per segment
#define OFF_SEL    4096       // int[8192]   packed e0|e1<<8
#define OFF_W0     36864      // float[8192]
#define OFF_W1     69632      // float[8192]
#define OFF_TOK    102400     // int[17408]  token id per routed h-row
#define OFF_SLOTW  172032     // float[17408] combine weight per routed h-row
#define OFF_XBF    262144     // bf16[8192*1024] x in bf16
#define OFF_SGT    17039360   // bf16 shared_gate^T [2048][1024]
#define OFF_SUT    21233664   // bf16 shared_up^T   [2048][1024]
#define OFF_SDT    25427968   // bf16 shared_down^T [1024][2048]
#define OFF_EGT    29622272   // bf16 exp_gate^T  8x[2048][1024]
#define OFF_EUT    63176704   // bf16 exp_up^T    8x[2048][1024]
#define OFF_EDT    96731136   // bf16 exp_down^T  8x[1024][2048]
#define OFF_H      130285568  // bf16[25600*2048] intermediate (weight folded in)

__device__ __forceinline__ void gl2lds16(const void* g, void* l) {
  __builtin_amdgcn_global_load_lds(
      (__attribute__((address_space(1))) void*)g,
      (__attribute__((address_space(3))) void*)l, 16, 0, 0);
}

// ---------------- router: logits, top-2, counts, P sums, x->bf16 ----------------
__global__ __launch_bounds__(256) void router_k(
    const float* __restrict__ x, const float* __restrict__ gw,
    __bf16* __restrict__ xbf, int* __restrict__ cnt, float* __restrict__ psum,
    int* __restrict__ sel, float* __restrict__ w0, float* __restrict__ w1)
{
  __shared__ int   s_cnt[NEXP];
  __shared__ float s_ps[NEXP];
  int tid = threadIdx.x;
  if (tid < NEXP) { s_cnt[tid] = 0; s_ps[tid] = 0.f; }
  __syncthreads();
  int wv = tid >> 6, lane = tid & 63;
  int tok = blockIdx.x * 4 + wv;

  float acc[NEXP];
#pragma unroll
  for (int e = 0; e < NEXP; ++e) acc[e] = 0.f;

  const float* xr = x + (size_t)tok * DIM;
#pragma unroll
  for (int i = 0; i < 4; ++i) {
    int c = i * 64 + lane;                      // chunk of 4 floats
    float4 xv = *(const float4*)(xr + c * 4);
    bf16x4 o = { (__bf16)xv.x, (__bf16)xv.y, (__bf16)xv.z, (__bf16)xv.w };
    *(bf16x4*)(xbf + (size_t)tok * DIM + c * 4) = o;
#pragma unroll
    for (int e = 0; e < NEXP; ++e) {
      float4 g = *(const float4*)(gw + e * DIM + c * 4);
      acc[e] += xv.x * g.x + xv.y * g.y + xv.z * g.z + xv.w * g.w;
    }
  }
#pragma unroll
  for (int e = 0; e < NEXP; ++e) {
#pragma unroll
    for (int off = 32; off > 0; off >>= 1)
      acc[e] += __shfl_xor(acc[e], off, 64);
  }
  if (lane == 0) {
    int e0 = 0; float v0 = acc[0];
    for (int e = 1; e < NEXP; ++e) if (acc[e] > v0) { v0 = acc[e]; e0 = e; }
    int e1 = -1; float v1 = -3.4e38f;
    for (int e = 0; e < NEXP; ++e) if (e != e0 && acc[e] > v1) { v1 = acc[e]; e1 = e; }
    float ew = __expf(v1 - v0);
    float inv2 = 1.f / (1.f + ew);
    sel[tok] = e0 | (e1 << 8);
    w0[tok] = inv2;          // weight of top-1
    w1[tok] = ew * inv2;     // weight of top-2
    // full softmax for aux P
    float s = 0.f, pe[NEXP];
    for (int e = 0; e < NEXP; ++e) { pe[e] = __expf(acc[e] - v0); s += pe[e]; }
    float inv = 1.f / s;
    atomicAdd(&s_cnt[e0], 1); atomicAdd(&s_cnt[e1], 1);
    for (int e = 0; e < NEXP; ++e) atomicAdd(&s_ps[e], pe[e] * inv);
  }
  __syncthreads();
  if (tid < NEXP) { atomicAdd(&cnt[tid], s_cnt[tid]); atomicAdd(&psum[tid], s_ps[tid]); }
}

// ---------------- segment offsets + aux loss ----------------
__global__ void offsets_k(const int* __restrict__ cnt, const float* __restrict__ psum,
                          int* __restrict__ segh, int* __restrict__ segc,
                          float* __restrict__ aux_out)
{
  if (threadIdx.x == 0) {
    segh[0] = 0; segc[0] = T_TOK;      // shared segment
    int base = T_TOK;
    float aux = 0.f;
    for (int e = 0; e < NEXP; ++e) {
      int c = cnt[e];
      segh[e + 1] = base;
      segc[e + 1] = c;
      base += (c + 127) & ~127;
      aux += ((float)c / (float)(T_TOK * 2)) * (psum[e] / (float)T_TOK);
    }
    *aux_out = (float)NEXP * aux;
  }
}

// ---------------- assign tokens to expert slots ----------------
__global__ __launch_bounds__(256) void assign_k(
    const int* __restrict__ sel, const float* __restrict__ w0, const float* __restrict__ w1,
    int* __restrict__ cursor, const int* __restrict__ segh,
    int* __restrict__ tok_arr, float* __restrict__ slotw)
{
  int t = blockIdx.x * 256 + threadIdx.x;
  int s = sel[t];
  int e0 = s & 0xff, e1 = s >> 8;
  int p0 = atomicAdd(&cursor[e0], 1);
  int i0 = segh[e0 + 1] - T_TOK + p0;
  tok_arr[i0] = t; slotw[i0] = w0[t];
  int p1 = atomicAdd(&cursor[e1], 1);
  int i1 = segh[e1 + 1] - T_TOK + p1;
  tok_arr[i1] = t; slotw[i1] = w1[t];
}

// ---------------- transpose + fp32->bf16 convert:  src[K][N] -> dst[N][K] ----------------
__global__ __launch_bounds__(256) void tconv_k(
    const float* __restrict__ src, __bf16* __restrict__ dst, int K, int N)
{
  __shared__ float t[64][65];
  size_t mo = (size_t)blockIdx.z * K * N;
  src += mo; dst += mo;
  int n0 = blockIdx.x * 64, k0 = blockIdx.y * 64;
  int tid = threadIdx.x;
  int r  = tid >> 4;           // 0..15
  int c4 = (tid & 15) * 4;     // 0..60
#pragma unroll
  for (int i = 0; i < 4; ++i) {
    int kk = r + i * 16;
    float4 v = *(const float4*)(src + (size_t)(k0 + kk) * N + n0 + c4);
    t[kk][c4 + 0] = v.x; t[kk][c4 + 1] = v.y; t[kk][c4 + 2] = v.z; t[kk][c4 + 3] = v.w;
  }
  __syncthreads();
#pragma unroll
  for (int i = 0; i < 4; ++i) {
    int nn = r + i * 16;
    bf16x4 o = { (__bf16)t[c4 + 0][nn], (__bf16)t[c4 + 1][nn],
                 (__bf16)t[c4 + 2][nn], (__bf16)t[c4 + 3][nn] };
    *(bf16x4*)(dst + (size_t)(n0 + nn) * K + k0 + c4) = o;
  }
}

// ---------------- fused gate+up GEMM:  h = silu(x Wg) * (x Wu) * w_row  (bf16) -------------
// Block: BM=128 rows x BN=64 cols, 256 thr (4 waves 2x2, wave = 64x32), K=1024, BK=32
__global__ __launch_bounds__(256) void gateup_k(
    const __bf16* __restrict__ xbf,
    const __bf16* __restrict__ sgT, const __bf16* __restrict__ suT,
    const __bf16* __restrict__ egT, const __bf16* __restrict__ euT,
    const int* __restrict__ segh, const int* __restrict__ segc,
    const int* __restrict__ tok_arr, const float* __restrict__ slotw,
    __bf16* __restrict__ h)
{
  int z = blockIdx.z;
  int cntv = segc[z];
  int m0 = blockIdx.y * 128;
  if (m0 >= cntv) return;
  int n0 = blockIdx.x * 64;
  int hs = segh[z];

  const __bf16 *bg, *bu;
  if (z == 0) { bg = sgT; bu = suT; }
  else {
    size_t eo = (size_t)(z - 1) * (IDIM * DIM);
    bg = egT + eo; bu = euT + eo;
  }

  __shared__ __bf16 sA[128 * 32];
  __shared__ __bf16 sBg[64 * 32];
  __shared__ __bf16 sBu[64 * 32];
  __shared__ int   s_off[128];
  __shared__ float s_w[128];

  int tid = threadIdx.x;
  if (tid < 128) {
    int lr = m0 + tid;
    int tok; float w;
    if (z == 0) { tok = lr; w = 1.0f; }
    else if (lr < cntv) { int idx = hs - T_TOK + lr; tok = tok_arr[idx]; w = slotw[idx]; }
    else { tok = 0; w = 0.f; }
    s_off[tid] = tok * DIM;
    s_w[tid] = w;
  }
  __syncthreads();

  int wv = tid >> 6, lane = tid & 63;
  int wm = wv & 1, wn = wv >> 1;

  // staging source (element offsets); advance by +32 per k-step
  int c0 = tid, c1 = 256 + tid;
  int aoff0 = s_off[c0 >> 2] + (c0 & 3) * 8;
  int aoff1 = s_off[c1 >> 2] + (c1 & 3) * 8;
  const __bf16* bgs = bg + (size_t)(n0 + (tid >> 2)) * DIM + (tid & 3) * 8;
  const __bf16* bus = bu + (size_t)(n0 + (tid >> 2)) * DIM + (tid & 3) * 8;
  char* ldsA0 = (char*)sA + wv * 1024;
  char* ldsA1 = (char*)sA + 4096 + wv * 1024;
  char* ldsBg = (char*)sBg + wv * 1024;
  char* ldsBu = (char*)sBu + wv * 1024;

  // fragment LDS base addresses (bytes); rows are 32 bf16 = 64 B
  const char* aBase  = (const char*)sA  + (wm * 64 + (lane & 15)) * 64 + (lane >> 4) * 16;
  const char* bgBase = (const char*)sBg + (wn * 32 + (lane & 15)) * 64 + (lane >> 4) * 16;
  const char* buBase = (const char*)sBu + (wn * 32 + (lane & 15)) * 64 + (lane >> 4) * 16;

  f32x4 accg[4][2], accu[4][2];
#pragma unroll
  for (int mi = 0; mi < 4; ++mi)
#pragma unroll
    for (int ni = 0; ni < 2; ++ni) {
      accg[mi][ni] = (f32x4){0.f, 0.f, 0.f, 0.f};
      accu[mi][ni] = (f32x4){0.f, 0.f, 0.f, 0.f};
    }

  for (int kt = 0; kt < DIM / 32; ++kt) {
    int k0 = kt * 32;
    __syncthreads();
    gl2lds16(xbf + aoff0 + k0, ldsA0);
    gl2lds16(xbf + aoff1 + k0, ldsA1);
    gl2lds16(bgs + k0, ldsBg);
    gl2lds16(bus + k0, ldsBu);
    __syncthreads();

    bf16x8 af[4], bgf[2], buf2[2];
#pragma unroll
    for (int mi = 0; mi < 4; ++mi) af[mi] = *(const bf16x8*)(aBase + mi * 16 * 64);
#pragma unroll
    for (int ni = 0; ni < 2; ++ni) {
      bgf[ni]  = *(const bf16x8*)(bgBase + ni * 16 * 64);
      buf2[ni] = *(const bf16x8*)(buBase + ni * 16 * 64);
    }
#pragma unroll
    for (int mi = 0; mi < 4; ++mi)
#pragma unroll
      for (int ni = 0; ni < 2; ++ni) {
        accg[mi][ni] = __builtin_amdgcn_mfma_f32_16x16x32_bf16(af[mi], bgf[ni],  accg[mi][ni], 0, 0, 0);
        accu[mi][ni] = __builtin_amdgcn_mfma_f32_16x16x32_bf16(af[mi], buf2[ni], accu[mi][ni], 0, 0, 0);
      }
  }

  // epilogue: h = silu(g)*u*w
  int colbase = n0 + wn * 32 + (lane & 15);
#pragma unroll
  for (int mi = 0; mi < 4; ++mi)
#pragma unroll
    for (int ni = 0; ni < 2; ++ni) {
      int col = colbase + ni * 16;
#pragma unroll
      for (int i = 0; i < 4; ++i) {
        int row = wm * 64 + mi * 16 + (lane >> 4) * 4 + i;
        float g = accg[mi][ni][i], u = accu[mi][ni][i];
        float hv = g / (1.f + __expf(-g)) * u * s_w[row];
        h[(size_t)(hs + m0 + row) * IDIM + col] = (__bf16)hv;
      }
    }
}

// ---------------- down GEMM: out += h Wd  (scatter via fp32 atomics) ----------------
// Block: BM=128 x BN=128, 256 thr (4 waves 2x2, wave = 64x64), K=2048, BK=32
__global__ __launch_bounds__(256) void down_k(
    const __bf16* __restrict__ h,
    const __bf16* __restrict__ sdT, const __bf16* __restrict__ edT,
    const int* __restrict__ segh, const int* __restrict__ segc,
    const int* __restrict__ tok_arr,
    float* __restrict__ out)
{
  int z = blockIdx.z;
  int cntv = segc[z];
  int m0 = blockIdx.y * 128;
  if (m0 >= cntv) return;
  int n0 = blockIdx.x * 128;
  int hs = segh[z];
  const __bf16* bw = (z == 0) ? sdT : edT + (size_t)(z - 1) * (IDIM * DIM);

  __shared__ __bf16 sA[128 * 32];
  __shared__ __bf16 sB[128 * 32];
  __shared__ int s_tok[128];

  int tid = threadIdx.x;
  if (tid < 128) {
    int lr = m0 + tid;
    int tok;
    if (z == 0) tok = lr;
    else tok = (lr < cntv) ? tok_arr[hs - T_TOK + lr] : 0;
    s_tok[tid] = tok;
  }
  __syncthreads();

  int wv = tid >> 6, lane = tid & 63;
  int wm = wv & 1, wn = wv >> 1;

  int c0 = tid, c1 = 256 + tid;
  const __bf16* as0 = h + (size_t)(hs + m0 + (c0 >> 2)) * IDIM + (c0 & 3) * 8;
  const __bf16* as1 = h + (size_t)(hs + m0 + (c1 >> 2)) * IDIM + (c1 & 3) * 8;
  const __bf16* bs0 = bw + (size_t)(n0 + (c0 >> 2)) * IDIM + (c0 & 3) * 8;
  const __bf16* bs1 = bw + (size_t)(n0 + (c1 >> 2)) * IDIM + (c1 & 3) * 8;
  char* ldsA0 = (char*)sA + wv * 1024;
  char* ldsA1 = (char*)sA + 4096 + wv * 1024;
  char* ldsB0 = (char*)sB + wv * 1024;
  char* ldsB1 = (char*)sB + 4096 + wv * 1024;

  const char* aBase = (const char*)sA + (wm * 64 + (lane & 15)) * 64 + (lane >> 4) * 16;
  const char* bBase = (const char*)sB + (wn * 64 + (lane & 15)) * 64 + (lane >> 4) * 16;

  f32x4 acc[4][4];
#pragma unroll
  for (int mi = 0; mi < 4; ++mi)
#pragma unroll
    for (int ni = 0; ni < 4; ++ni) acc[mi][ni] = (f32x4){0.f, 0.f, 0.f, 0.f};

  for (int kt = 0; kt < IDIM / 32; ++kt) {
    int k0 = kt * 32;
    __syncthreads();
    gl2lds16(as0 + k0, ldsA0);
    gl2lds16(as1 + k0, ldsA1);
    gl2lds16(bs0 + k0, ldsB0);
    gl2lds16(bs1 + k0, ldsB1);
    __syncthreads();

    bf16x8 af[4], bf[4];
#pragma unroll
    for (int mi = 0; mi < 4; ++mi) af[mi] = *(const bf16x8*)(aBase + mi * 16 * 64);
#pragma unroll
    for (int ni = 0; ni < 4; ++ni) bf[ni] = *(const bf16x8*)(bBase + ni * 16 * 64);
#pragma unroll
    for (int mi = 0; mi < 4; ++mi)
#pragma unroll
      for (int ni = 0; ni < 4; ++ni)
        acc[mi][ni] = __builtin_amdgcn_mfma_f32_16x16x32_bf16(af[mi], bf[ni], acc[mi][ni], 0, 0, 0);
  }

#pragma unroll
  for (int mi = 0; mi < 4; ++mi)
#pragma unroll
    for (int ni = 0; ni < 4; ++ni) {
      int col = n0 + wn * 64 + ni * 16 + (lane & 15);
#pragma unroll
      for (int i = 0; i < 4; ++i) {
        int row = wm * 64 + mi * 16 + (lane >> 4) * 4 + i;
        atomicAdd(&out[(size_t)s_tok[row] * DIM + col], acc[mi][ni][i]);
      }
    }
}

// ---------------- launch ----------------
extern "C" void kernel_launch(void* const* d_in, const int* in_sizes, int n_in,
                              void* d_out, int out_size, void* d_ws, size_t ws_size,
                              hipStream_t stream) {
  const float* x  = (const float*)d_in[0];
  const float* gw = (const float*)d_in[1];
  const float* sg = (const float*)d_in[2];
  const float* su = (const float*)d_in[3];
  const float* sd = (const float*)d_in[4];
  const float* eg = (const float*)d_in[5];
  const float* eu = (const float*)d_in[6];
  const float* ed = (const float*)d_in[7];
  float* out = (float*)d_out;
  char* ws = (char*)d_ws;

  int*    cnt    = (int*)(ws + OFF_CNT);
  float*  psum   = (float*)(ws + OFF_PSUM);
  int*    cursor = (int*)(ws + OFF_CUR);
  int*    segh   = (int*)(ws + OFF_SEGH);
  int*    segc   = (int*)(ws + OFF_SEGC);
  int*    sel    = (int*)(ws + OFF_SEL);
  float*  w0     = (float*)(ws + OFF_W0);
  float*  w1     = (float*)(ws + OFF_W1);
  int*    tokar  = (int*)(ws + OFF_TOK);
  float*  slotw  = (float*)(ws + OFF_SLOTW);
  __bf16* xbf    = (__bf16*)(ws + OFF_XBF);
  __bf16* sgT    = (__bf16*)(ws + OFF_SGT);
  __bf16* suT    = (__bf16*)(ws + OFF_SUT);
  __bf16* sdT    = (__bf16*)(ws + OFF_SDT);
  __bf16* egT    = (__bf16*)(ws + OFF_EGT);
  __bf16* euT    = (__bf16*)(ws + OFF_EUT);
  __bf16* edT    = (__bf16*)(ws + OFF_EDT);
  __bf16* hbuf   = (__bf16*)(ws + OFF_H);

  hipMemsetAsync(ws, 0, 512, stream);
  hipMemsetAsync(d_out, 0, (size_t)out_size * sizeof(float), stream);

  router_k<<<T_TOK / 4, 256, 0, stream>>>(x, gw, xbf, cnt, psum, sel, w0, w1);

  tconv_k<<<dim3(IDIM / 64, DIM / 64, 1), 256, 0, stream>>>(sg, sgT, DIM, IDIM);
  tconv_k<<<dim3(IDIM / 64, DIM / 64, 1), 256, 0, stream>>>(su, suT, DIM, IDIM);
  tconv_k<<<dim3(DIM / 64, IDIM / 64, 1), 256, 0, stream>>>(sd, sdT, IDIM, DIM);
  tconv_k<<<dim3(IDIM / 64, DIM / 64, NEXP), 256, 0, stream>>>(eg, egT, DIM, IDIM);
  tconv_k<<<dim3(IDIM / 64, DIM / 64, NEXP), 256, 0, stream>>>(eu, euT, DIM, IDIM);
  tconv_k<<<dim3(DIM / 64, IDIM / 64, NEXP), 256, 0, stream>>>(ed, edT, IDIM, DIM);

  offsets_k<<<1, 64, 0, stream>>>(cnt, psum, segh, segc, out + (size_t)T_TOK * DIM);
  assign_k<<<T_TOK / 256, 256, 0, stream>>>(sel, w0, w1, cursor, segh, tokar, slotw);

  // 9 segments: z=0 shared (all tokens), z=1..8 experts (early-exit past count)
  gateup_k<<<dim3(IDIM / 64, 64, 9), 256, 0, stream>>>(
      xbf, sgT, suT, egT, euT, segh, segc, tokar, slotw, hbuf);
  down_k<<<dim3(DIM / 128, 64, 9), 256, 0, stream>>>(
      hbuf, sdT, edT, segh, segc, tokar, out);
}

// Round 2
// 776.426 us; speedup vs baseline: 1.2159x; 1.2159x over previous
//
#include <hip/hip_runtime.h>
#include <hip/hip_bf16.h>
#include <stdint.h>

// Problem constants
#define T_TOK 8192
#define DIM   1024
#define IDIM  2048
#define NEXP  8
#define NBLK_R 2048   // router blocks (4 tokens each)

typedef __bf16 bf16x8 __attribute__((ext_vector_type(8)));
typedef __bf16 bf16x4 __attribute__((ext_vector_type(4)));
typedef float  f32x4  __attribute__((ext_vector_type(4)));

// ---------------- workspace layout (bytes) ----------------
#define OFF_CUR    0          // int[8] assign cursors (zeroed)
#define OFF_SEGH   64         // int[16]
#define OFF_SEGC   128        // int[16]
#define OFF_PCNT   4096       // int[2048*8] per-block expert counts
#define OFF_PPS    69632      // float[2048*8] per-block softmax-prob sums
#define OFF_SEL    135168     // int[8192] packed e0|e1<<8
#define OFF_W0     167936     // float[8192]
#define OFF_W1     200704     // float[8192]
#define OFF_TOK    233472     // int[17408] token id per routed h-row
#define OFF_SLOTW  303104     // float[17408]
#define OFF_S0     372736     // int[8192] routed slot of top-1
#define OFF_S1     405504     // int[8192] routed slot of top-2
#define OFF_XBF    524288     // bf16[8192*1024]
#define OFF_SGT    17301504   // bf16 shared_gate^T [2048][1024]
#define OFF_SUT    21495808   // bf16 shared_up^T
#define OFF_SDT    25690112   // bf16 shared_down^T [1024][2048]
#define OFF_EGT    29884416   // bf16 exp_gate^T 8x
#define OFF_EUT    63438848   // bf16 exp_up^T 8x
#define OFF_EDT    96993280   // bf16 exp_down^T 8x
#define OFF_H      130547712  // bf16[25600*2048]
// y (fp32, routed rows only, 17408*1024*4 = 71.3MB) overlays XBF..EUT which are
// dead after gateup_k completes (stream-ordered before down_k).
#define OFF_Y      524288

__device__ __forceinline__ void gl2lds16(const void* g, void* l) {
  __builtin_amdgcn_global_load_lds(
      (__attribute__((address_space(1))) void*)g,
      (__attribute__((address_space(3))) void*)l, 16, 0, 0);
}

// ---------------- router: logits, top-2, per-block partials, x->bf16 ----------------
__global__ __launch_bounds__(256) void router_k(
    const float* __restrict__ x, const float* __restrict__ gw,
    __bf16* __restrict__ xbf, int* __restrict__ pcnt, float* __restrict__ pps,
    int* __restrict__ sel, float* __restrict__ w0, float* __restrict__ w1)
{
  __shared__ int   s_cnt[NEXP];
  __shared__ float s_ps[NEXP];
  int tid = threadIdx.x;
  if (tid < NEXP) { s_cnt[tid] = 0; s_ps[tid] = 0.f; }
  __syncthreads();
  int wv = tid >> 6, lane = tid & 63;
  int tok = blockIdx.x * 4 + wv;

  float acc[NEXP];
#pragma unroll
  for (int e = 0; e < NEXP; ++e) acc[e] = 0.f;

  const float* xr = x + (size_t)tok * DIM;
#pragma unroll
  for (int i = 0; i < 4; ++i) {
    int c = i * 64 + lane;
    float4 xv = *(const float4*)(xr + c * 4);
    bf16x4 o = { (__bf16)xv.x, (__bf16)xv.y, (__bf16)xv.z, (__bf16)xv.w };
    *(bf16x4*)(xbf + (size_t)tok * DIM + c * 4) = o;
#pragma unroll
    for (int e = 0; e < NEXP; ++e) {
      float4 g = *(const float4*)(gw + e * DIM + c * 4);
      acc[e] += xv.x * g.x + xv.y * g.y + xv.z * g.z + xv.w * g.w;
    }
  }
#pragma unroll
  for (int e = 0; e < NEXP; ++e) {
#pragma unroll
    for (int off = 32; off > 0; off >>= 1)
      acc[e] += __shfl_xor(acc[e], off, 64);
  }
  if (lane == 0) {
    int e0 = 0; float v0 = acc[0];
    for (int e = 1; e < NEXP; ++e) if (acc[e] > v0) { v0 = acc[e]; e0 = e; }
    int e1 = -1; float v1 = -3.4e38f;
    for (int e = 0; e < NEXP; ++e) if (e != e0 && acc[e] > v1) { v1 = acc[e]; e1 = e; }
    float ew = __expf(v1 - v0);
    float inv2 = 1.f / (1.f + ew);
    sel[tok] = e0 | (e1 << 8);
    w0[tok] = inv2;
    w1[tok] = ew * inv2;
    float s = 0.f, pe[NEXP];
    for (int e = 0; e < NEXP; ++e) { pe[e] = __expf(acc[e] - v0); s += pe[e]; }
    float inv = 1.f / s;
    atomicAdd(&s_cnt[e0], 1); atomicAdd(&s_cnt[e1], 1);
    for (int e = 0; e < NEXP; ++e) atomicAdd(&s_ps[e], pe[e] * inv);
  }
  __syncthreads();
  if (tid < NEXP) {
    pcnt[blockIdx.x * NEXP + tid] = s_cnt[tid];
    pps[blockIdx.x * NEXP + tid]  = s_ps[tid];
  }
}

// ---------------- reduce partials -> segments + aux ----------------
__global__ __launch_bounds__(256) void offsets_k(
    const int* __restrict__ pcnt, const float* __restrict__ pps,
    int* __restrict__ segh, int* __restrict__ segc, float* __restrict__ aux_out)
{
  __shared__ int   scnt[NEXP];
  __shared__ float sps[NEXP];
  int tid = threadIdx.x;
  if (tid < NEXP) { scnt[tid] = 0; sps[tid] = 0.f; }
  __syncthreads();
  int e = tid & 7, chunk = tid >> 3;          // 32 chunks of 64 blocks
  int cs = 0; float fs = 0.f;
  for (int b = chunk * (NBLK_R / 32); b < (chunk + 1) * (NBLK_R / 32); ++b) {
    cs += pcnt[b * NEXP + e];
    fs += pps[b * NEXP + e];
  }
  atomicAdd(&scnt[e], cs);
  atomicAdd(&sps[e], fs);
  __syncthreads();
  if (tid == 0) {
    int base = T_TOK; float aux = 0.f;
    segh[0] = 0; segc[0] = T_TOK;
    for (int k = 0; k < NEXP; ++k) {
      int c = scnt[k];
      segh[k + 1] = base;
      segc[k + 1] = c;
      base += (c + 127) & ~127;
      aux += ((float)c / (float)(T_TOK * 2)) * (sps[k] / (float)T_TOK);
    }
    *aux_out = (float)NEXP * aux;
  }
}

// ---------------- assign tokens to expert slots (block-aggregated cursors) ----------------
__global__ __launch_bounds__(256) void assign_k(
    const int* __restrict__ sel, const float* __restrict__ w0, const float* __restrict__ w1,
    int* __restrict__ cursor, const int* __restrict__ segh,
    int* __restrict__ tok_arr, float* __restrict__ slotw,
    int* __restrict__ slot0, int* __restrict__ slot1)
{
  __shared__ int lcnt[NEXP], lbase[NEXP];
  int tid = threadIdx.x;
  if (tid < NEXP) lcnt[tid] = 0;
  __syncthreads();
  int t = blockIdx.x * 256 + tid;
  int s = sel[t];
  int e0 = s & 0xff, e1 = s >> 8;
  int lp0 = atomicAdd(&lcnt[e0], 1);
  int lp1 = atomicAdd(&lcnt[e1], 1);
  __syncthreads();
  if (tid < NEXP) lbase[tid] = atomicAdd(&cursor[tid], lcnt[tid]);
  __syncthreads();
  int i0 = segh[e0 + 1] - T_TOK + lbase[e0] + lp0;
  int i1 = segh[e1 + 1] - T_TOK + lbase[e1] + lp1;
  tok_arr[i0] = t; slotw[i0] = w0[t]; slot0[t] = i0;
  tok_arr[i1] = t; slotw[i1] = w1[t]; slot1[t] = i1;
}

// ---------------- transpose + fp32->bf16:  src[K][N] -> dst[N][K] ----------------
__global__ __launch_bounds__(256) void tconv_k(
    const float* __restrict__ src, __bf16* __restrict__ dst, int K, int N)
{
  __shared__ float t[64][65];
  size_t mo = (size_t)blockIdx.z * K * N;
  src += mo; dst += mo;
  int n0 = blockIdx.x * 64, k0 = blockIdx.y * 64;
  int tid = threadIdx.x;
  int r  = tid >> 4;
  int c4 = (tid & 15) * 4;
#pragma unroll
  for (int i = 0; i < 4; ++i) {
    int kk = r + i * 16;
    float4 v = *(const float4*)(src + (size_t)(k0 + kk) * N + n0 + c4);
    t[kk][c4 + 0] = v.x; t[kk][c4 + 1] = v.y; t[kk][c4 + 2] = v.z; t[kk][c4 + 3] = v.w;
  }
  __syncthreads();
#pragma unroll
  for (int i = 0; i < 4; ++i) {
    int nn = r + i * 16;
    bf16x4 o = { (__bf16)t[c4 + 0][nn], (__bf16)t[c4 + 1][nn],
                 (__bf16)t[c4 + 2][nn], (__bf16)t[c4 + 3][nn] };
    *(bf16x4*)(dst + (size_t)(n0 + nn) * K + k0 + c4) = o;
  }
}

// ---------------- fused gate+up GEMM (XOR-swizzled LDS) ----------------
// Block: BM=128 x BN=64, 256 thr (4 waves 2x2), K=1024, BK=32
__global__ __launch_bounds__(256) void gateup_k(
    const __bf16* __restrict__ xbf,
    const __bf16* __restrict__ sgT, const __bf16* __restrict__ suT,
    const __bf16* __restrict__ egT, const __bf16* __restrict__ euT,
    const int* __restrict__ segh, const int* __restrict__ segc,
    const int* __restrict__ tok_arr, const float* __restrict__ slotw,
    __bf16* __restrict__ h)
{
  int z = blockIdx.z;
  int cntv = segc[z];
  int m0 = blockIdx.y * 128;
  if (m0 >= cntv) return;
  int n0 = blockIdx.x * 64;
  int hs = segh[z];

  const __bf16 *bg, *bu;
  if (z == 0) { bg = sgT; bu = suT; }
  else {
    size_t eo = (size_t)(z - 1) * (IDIM * DIM);
    bg = egT + eo; bu = euT + eo;
  }

  __shared__ __bf16 sA[128 * 32];
  __shared__ __bf16 sBg[64 * 32];
  __shared__ __bf16 sBu[64 * 32];
  __shared__ int   s_off[128];
  __shared__ float s_w[128];

  int tid = threadIdx.x;
  if (tid < 128) {
    int lr = m0 + tid;
    int tok; float w;
    if (z == 0) { tok = lr; w = 1.0f; }
    else if (lr < cntv) { int idx = hs - T_TOK + lr; tok = tok_arr[idx]; w = slotw[idx]; }
    else { tok = 0; w = 0.f; }
    s_off[tid] = tok * DIM;
    s_w[tid] = w;
  }
  __syncthreads();

  int wv = tid >> 6, lane = tid & 63;
  int wm = wv & 1, wn = wv >> 1;

  // XOR-swizzled staging: thread tid owns physical slot (row=tid>>2, pc=tid&3);
  // logical col = pc ^ ((row>>1)&3)  (16-row shifts don't change the xor term)
  int sw = (((tid & 3) ^ ((tid >> 3) & 3)) * 8);
  int aoff0 = s_off[tid >> 2] + sw;
  int aoff1 = s_off[64 + (tid >> 2)] + sw;
  const __bf16* bgs = bg + (size_t)(n0 + (tid >> 2)) * DIM + sw;
  const __bf16* bus = bu + (size_t)(n0 + (tid >> 2)) * DIM + sw;
  char* ldsA0 = (char*)sA + wv * 1024;
  char* ldsA1 = (char*)sA + 4096 + wv * 1024;
  char* ldsBg = (char*)sBg + wv * 1024;
  char* ldsBu = (char*)sBu + wv * 1024;

  // fragment bases with matching xor
  int fr = lane & 15;
  int fx = ((lane >> 4) ^ ((fr >> 1) & 3)) * 16;
  const char* aBase  = (const char*)sA  + (wm * 64 + fr) * 64 + fx;
  const char* bgBase = (const char*)sBg + (wn * 32 + fr) * 64 + fx;
  const char* buBase = (const char*)sBu + (wn * 32 + fr) * 64 + fx;

  f32x4 accg[4][2], accu[4][2];
#pragma unroll
  for (int mi = 0; mi < 4; ++mi)
#pragma unroll
    for (int ni = 0; ni < 2; ++ni) {
      accg[mi][ni] = (f32x4){0.f, 0.f, 0.f, 0.f};
      accu[mi][ni] = (f32x4){0.f, 0.f, 0.f, 0.f};
    }

  for (int kt = 0; kt < DIM / 32; ++kt) {
    int k0 = kt * 32;
    __syncthreads();
    gl2lds16(xbf + aoff0 + k0, ldsA0);
    gl2lds16(xbf + aoff1 + k0, ldsA1);
    gl2lds16(bgs + k0, ldsBg);
    gl2lds16(bus + k0, ldsBu);
    __syncthreads();

    bf16x8 af[4], bgf[2], buf2[2];
#pragma unroll
    for (int mi = 0; mi < 4; ++mi) af[mi] = *(const bf16x8*)(aBase + mi * 16 * 64);
#pragma unroll
    for (int ni = 0; ni < 2; ++ni) {
      bgf[ni]  = *(const bf16x8*)(bgBase + ni * 16 * 64);
      buf2[ni] = *(const bf16x8*)(buBase + ni * 16 * 64);
    }
#pragma unroll
    for (int mi = 0; mi < 4; ++mi)
#pragma unroll
      for (int ni = 0; ni < 2; ++ni) {
        accg[mi][ni] = __builtin_amdgcn_mfma_f32_16x16x32_bf16(af[mi], bgf[ni],  accg[mi][ni], 0, 0, 0);
        accu[mi][ni] = __builtin_amdgcn_mfma_f32_16x16x32_bf16(af[mi], buf2[ni], accu[mi][ni], 0, 0, 0);
      }
  }

  int colbase = n0 + wn * 32 + (lane & 15);
#pragma unroll
  for (int mi = 0; mi < 4; ++mi)
#pragma unroll
    for (int ni = 0; ni < 2; ++ni) {
      int col = colbase + ni * 16;
#pragma unroll
      for (int i = 0; i < 4; ++i) {
        int row = wm * 64 + mi * 16 + (lane >> 4) * 4 + i;
        float g = accg[mi][ni][i], u = accu[mi][ni][i];
        float hv = g / (1.f + __expf(-g)) * u * s_w[row];
        h[(size_t)(hs + m0 + row) * IDIM + col] = (__bf16)hv;
      }
    }
}

// ---------------- down GEMM: seg0 -> out (stores), experts -> y (stores) ----------------
// Block: BM=128 x BN=128, 256 thr (4 waves 2x2), K=2048, BK=32
__global__ __launch_bounds__(256) void down_k(
    const __bf16* __restrict__ h,
    const __bf16* __restrict__ sdT, const __bf16* __restrict__ edT,
    const int* __restrict__ segh, const int* __restrict__ segc,
    float* __restrict__ out, float* __restrict__ y)
{
  int z = blockIdx.z;
  int cntv = segc[z];
  int m0 = blockIdx.y * 128;
  if (m0 >= cntv) return;
  int n0 = blockIdx.x * 128;
  int hs = segh[z];
  const __bf16* bw = (z == 0) ? sdT : edT + (size_t)(z - 1) * (IDIM * DIM);

  __shared__ __bf16 sA[128 * 32];
  __shared__ __bf16 sB[128 * 32];

  int tid = threadIdx.x;
  int wv = tid >> 6, lane = tid & 63;
  int wm = wv & 1, wn = wv >> 1;

  int sw = (((tid & 3) ^ ((tid >> 3) & 3)) * 8);
  const __bf16* as0 = h + (size_t)(hs + m0 + (tid >> 2)) * IDIM + sw;
  const __bf16* as1 = h + (size_t)(hs + m0 + 64 + (tid >> 2)) * IDIM + sw;
  const __bf16* bs0 = bw + (size_t)(n0 + (tid >> 2)) * IDIM + sw;
  const __bf16* bs1 = bw + (size_t)(n0 + 64 + (tid >> 2)) * IDIM + sw;
  char* ldsA0 = (char*)sA + wv * 1024;
  char* ldsA1 = (char*)sA + 4096 + wv * 1024;
  char* ldsB0 = (char*)sB + wv * 1024;
  char* ldsB1 = (char*)sB + 4096 + wv * 1024;

  int fr = lane & 15;
  int fx = ((lane >> 4) ^ ((fr >> 1) & 3)) * 16;
  const char* aBase = (const char*)sA + (wm * 64 + fr) * 64 + fx;
  const char* bBase = (const char*)sB + (wn * 64 + fr) * 64 + fx;

  f32x4 acc[4][4];
#pragma unroll
  for (int mi = 0; mi < 4; ++mi)
#pragma unroll
    for (int ni = 0; ni < 4; ++ni) acc[mi][ni] = (f32x4){0.f, 0.f, 0.f, 0.f};

  for (int kt = 0; kt < IDIM / 32; ++kt) {
    int k0 = kt * 32;
    __syncthreads();
    gl2lds16(as0 + k0, ldsA0);
    gl2lds16(as1 + k0, ldsA1);
    gl2lds16(bs0 + k0, ldsB0);
    gl2lds16(bs1 + k0, ldsB1);
    __syncthreads();

    bf16x8 af[4], bf[4];
#pragma unroll
    for (int mi = 0; mi < 4; ++mi) af[mi] = *(const bf16x8*)(aBase + mi * 16 * 64);
#pragma unroll
    for (int ni = 0; ni < 4; ++ni) bf[ni] = *(const bf16x8*)(bBase + ni * 16 * 64);
#pragma unroll
    for (int mi = 0; mi < 4; ++mi)
#pragma unroll
      for (int ni = 0; ni < 4; ++ni)
        acc[mi][ni] = __builtin_amdgcn_mfma_f32_16x16x32_bf16(af[mi], bf[ni], acc[mi][ni], 0, 0, 0);
  }

  if (z == 0) {
#pragma unroll
    for (int mi = 0; mi < 4; ++mi)
#pragma unroll
      for (int ni = 0; ni < 4; ++ni) {
        int col = n0 + wn * 64 + ni * 16 + (lane & 15);
#pragma unroll
        for (int i = 0; i < 4; ++i) {
          int row = wm * 64 + mi * 16 + (lane >> 4) * 4 + i;
          out[(size_t)(m0 + row) * DIM + col] = acc[mi][ni][i];
        }
      }
  } else {
    float* yb = y + (size_t)(hs - T_TOK + m0) * DIM;
#pragma unroll
    for (int mi = 0; mi < 4; ++mi)
#pragma unroll
      for (int ni = 0; ni < 4; ++ni) {
        int col = n0 + wn * 64 + ni * 16 + (lane & 15);
#pragma unroll
        for (int i = 0; i < 4; ++i) {
          int row = wm * 64 + mi * 16 + (lane >> 4) * 4 + i;
          yb[(size_t)row * DIM + col] = acc[mi][ni][i];
        }
      }
  }
}

// ---------------- combine: out[t] += y[slot0] + y[slot1] ----------------
__global__ __launch_bounds__(256) void combine_k(
    const float* __restrict__ y, const int* __restrict__ slot0,
    const int* __restrict__ slot1, float* __restrict__ out)
{
  int t = blockIdx.x, tid = threadIdx.x;
  int r0 = slot0[t], r1 = slot1[t];
  const f32x4* ov = (const f32x4*)(out + (size_t)t * DIM);
  const f32x4* a  = (const f32x4*)(y + (size_t)r0 * DIM);
  const f32x4* b  = (const f32x4*)(y + (size_t)r1 * DIM);
  f32x4 v = ov[tid] + a[tid] + b[tid];
  ((f32x4*)(out + (size_t)t * DIM))[tid] = v;
}

// ---------------- launch ----------------
extern "C" void kernel_launch(void* const* d_in, const int* in_sizes, int n_in,
                              void* d_out, int out_size, void* d_ws, size_t ws_size,
                              hipStream_t stream) {
  const float* x  = (const float*)d_in[0];
  const float* gw = (const float*)d_in[1];
  const float* sg = (const float*)d_in[2];
  const float* su = (const float*)d_in[3];
  const float* sd = (const float*)d_in[4];
  const float* eg = (const float*)d_in[5];
  const float* eu = (const float*)d_in[6];
  const float* ed = (const float*)d_in[7];
  float* out = (float*)d_out;
  char* ws = (char*)d_ws;

  int*    cursor = (int*)(ws + OFF_CUR);
  int*    segh   = (int*)(ws + OFF_SEGH);
  int*    segc   = (int*)(ws + OFF_SEGC);
  int*    pcnt   = (int*)(ws + OFF_PCNT);
  float*  pps    = (float*)(ws + OFF_PPS);
  int*    sel    = (int*)(ws + OFF_SEL);
  float*  w0     = (float*)(ws + OFF_W0);
  float*  w1     = (float*)(ws + OFF_W1);
  int*    tokar  = (int*)(ws + OFF_TOK);
  float*  slotw  = (float*)(ws + OFF_SLOTW);
  int*    slot0  = (int*)(ws + OFF_S0);
  int*    slot1  = (int*)(ws + OFF_S1);
  __bf16* xbf    = (__bf16*)(ws + OFF_XBF);
  __bf16* sgT    = (__bf16*)(ws + OFF_SGT);
  __bf16* suT    = (__bf16*)(ws + OFF_SUT);
  __bf16* sdT    = (__bf16*)(ws + OFF_SDT);
  __bf16* egT    = (__bf16*)(ws + OFF_EGT);
  __bf16* euT    = (__bf16*)(ws + OFF_EUT);
  __bf16* edT    = (__bf16*)(ws + OFF_EDT);
  __bf16* hbuf   = (__bf16*)(ws + OFF_H);
  float*  ybuf   = (float*)(ws + OFF_Y);

  hipMemsetAsync(ws, 0, 256, stream);   // cursors (+segh/segc scratch)

  router_k<<<NBLK_R, 256, 0, stream>>>(x, gw, xbf, pcnt, pps, sel, w0, w1);

  tconv_k<<<dim3(IDIM / 64, DIM / 64, 1), 256, 0, stream>>>(sg, sgT, DIM, IDIM);
  tconv_k<<<dim3(IDIM / 64, DIM / 64, 1), 256, 0, stream>>>(su, suT, DIM, IDIM);
  tconv_k<<<dim3(DIM / 64, IDIM / 64, 1), 256, 0, stream>>>(sd, sdT, IDIM, DIM);
  tconv_k<<<dim3(IDIM / 64, DIM / 64, NEXP), 256, 0, stream>>>(eg, egT, DIM, IDIM);
  tconv_k<<<dim3(IDIM / 64, DIM / 64, NEXP), 256, 0, stream>>>(eu, euT, DIM, IDIM);
  tconv_k<<<dim3(DIM / 64, IDIM / 64, NEXP), 256, 0, stream>>>(ed, edT, IDIM, DIM);

  offsets_k<<<1, 256, 0, stream>>>(pcnt, pps, segh, segc, out + (size_t)T_TOK * DIM);
  assign_k<<<T_TOK / 256, 256, 0, stream>>>(sel, w0, w1, cursor, segh,
                                            tokar, slotw, slot0, slot1);

  gateup_k<<<dim3(IDIM / 64, 64, 9), 256, 0, stream>>>(
      xbf, sgT, suT, egT, euT, segh, segc, tokar, slotw, hbuf);
  down_k<<<dim3(DIM / 128, 64, 9), 256, 0, stream>>>(
      hbuf, sdT, edT, segh, segc, out, ybuf);
  combine_k<<<T_TOK, 256, 0, stream>>>(ybuf, slot0, slot1, out);
}